// Round 7
// baseline (156.435 us; speedup 1.0000x reference)
//
#include <hip/hip_runtime.h>
#include <hip/hip_bf16.h>

#define B_SZ 1024
#define F_SZ 2048
#define NK   32
#define NCOL 256            // NK*KD
#define OUTF 2080           // F + NK
#define NBLK 256
#define NTHR 512

typedef __attribute__((ext_vector_type(8))) short short8v;
typedef __attribute__((ext_vector_type(4))) short short4v;
typedef __attribute__((ext_vector_type(4))) float f32x4;

static __device__ __forceinline__ unsigned short f2bf(float v) {
  __hip_bfloat16 h = __float2bfloat16(v);   // RNE
  return reinterpret_cast<unsigned short&>(h);
}

// Device-scope arrive/spin barrier (counters memset to 0 before launch).
// All 256 blocks are co-resident (launch_bounds(512,4) => 2 blocks/CU capacity).
static __device__ __forceinline__ void barrier_arrive(unsigned* c) {
  __builtin_amdgcn_fence(__ATOMIC_RELEASE, "agent");   // push m/wt writes to agent visibility
  __syncthreads();
  if (threadIdx.x == 0)
    __hip_atomic_fetch_add(c, 1u, __ATOMIC_RELAXED, __HIP_MEMORY_SCOPE_AGENT);
}
static __device__ __forceinline__ void barrier_wait(unsigned* c) {
  if (threadIdx.x == 0) {
    for (int it = 0; it < 2000000; ++it) {             // bounded: fail visibly, never hang
      if (__hip_atomic_load(c, __ATOMIC_RELAXED, __HIP_MEMORY_SCOPE_AGENT) >= NBLK) break;
      __builtin_amdgcn_s_sleep(2);
    }
  }
  __syncthreads();
  __builtin_amdgcn_fence(__ATOMIC_ACQUIRE, "agent");   // invalidate stale L1/L2 lines
}

// ---------------------------------------------------------------------------
// Single fused kernel, 256 blocks x 512 thr, 2 software grid barriers:
//   P0 transpose W->wt(bf16)  | barA |  P1 GEMM->m  | arriveB |
//   P2 copy x->out (hides barrier skew)  | waitB |  P3 pairwise->out
// ---------------------------------------------------------------------------
__global__ __launch_bounds__(NTHR, 4) void mega(
    const float* __restrict__ x, const float* __restrict__ W,
    float* __restrict__ out, unsigned short* __restrict__ wt,
    float* __restrict__ m, unsigned* __restrict__ ctr) {
  __shared__ __align__(16) char smem[32768];   // union: P0 tile / P1 red / P3 red2
  int bid = blockIdx.x, t = threadIdx.x;

  // ---- P0: W[2048][256] f32 -> wt[256][2048] bf16.  Block: 128k x 16n tile. ----
  {
    typedef unsigned short tile_t[128][19];    // pad 19 -> 2-way max on read
    tile_t& tile = *reinterpret_cast<tile_t*>(smem);
    int kt = bid & 15, ntile = bid >> 4;
    int k0 = kt * 128, n0 = ntile * 16;
    int lr = t >> 4, lc = t & 15;
#pragma unroll
    for (int u = 0; u < 4; ++u) {              // coalesced: 4 x 64B segments per wave
      int row = u * 32 + lr;
      tile[row][lc] = f2bf(W[(size_t)(k0 + row) * NCOL + n0 + lc]);
    }
    __syncthreads();
    int c = t >> 5, kq = (t & 31) * 4;
    short4v o;
#pragma unroll
    for (int u = 0; u < 4; ++u) o[u] = (short)tile[kq + u][c];
    *reinterpret_cast<short4v*>(&wt[(size_t)(n0 + c) * F_SZ + k0 + kq]) = o;  // 256B contig per 32 lanes
  }
  barrier_arrive(&ctr[0]);
  barrier_wait(&ctr[0]);

  // ---- P1: barrier-free GEMM.  m = x . W  (32x32 tile/block, 8 waves split K) ----
  {
    typedef float red_t[8][16][64];            // 32 KB
    red_t& red = *reinterpret_cast<red_t*>(smem);
    int mt = bid & 31, nt = bid >> 5;          // same-mt blocks share an XCD (bid mod 8)
    int i0 = mt * 32, n0 = nt * 32;
    int w = t >> 6, l = t & 63;
    int hi = l >> 4, r16 = l & 15;
    int hi8 = hi * 8;

    f32x4 acc[2][2];
#pragma unroll
    for (int mi = 0; mi < 2; ++mi)
#pragma unroll
      for (int ni = 0; ni < 2; ++ni) acc[mi][ni] = (f32x4)(0.f);

    for (int ks = 0; ks < 8; ++ks) {           // wave-private K chunk, no barriers
      int kc = w * 256 + ks * 32;
      short8v af[2];
#pragma unroll
      for (int mi = 0; mi < 2; ++mi) {
        const float* ap = &x[(size_t)(i0 + mi * 16 + r16) * F_SZ + kc + hi8];
        float4 v0 = *reinterpret_cast<const float4*>(ap);
        float4 v1 = *reinterpret_cast<const float4*>(ap + 4);
        af[mi][0] = (short)f2bf(v0.x); af[mi][1] = (short)f2bf(v0.y);
        af[mi][2] = (short)f2bf(v0.z); af[mi][3] = (short)f2bf(v0.w);
        af[mi][4] = (short)f2bf(v1.x); af[mi][5] = (short)f2bf(v1.y);
        af[mi][6] = (short)f2bf(v1.z); af[mi][7] = (short)f2bf(v1.w);
      }
      short8v bfr[2];
#pragma unroll
      for (int ni = 0; ni < 2; ++ni)           // contiguous 16B bf16 loads from wt
        bfr[ni] = *reinterpret_cast<const short8v*>(
            &wt[(size_t)(n0 + ni * 16 + r16) * F_SZ + kc + hi8]);
#pragma unroll
      for (int mi = 0; mi < 2; ++mi)
#pragma unroll
        for (int ni = 0; ni < 2; ++ni)
          acc[mi][ni] = __builtin_amdgcn_mfma_f32_16x16x32_bf16(
              af[mi], bfr[ni], acc[mi][ni], 0, 0, 0);
    }

#pragma unroll
    for (int mi = 0; mi < 2; ++mi)
#pragma unroll
      for (int ni = 0; ni < 2; ++ni)
#pragma unroll
        for (int r = 0; r < 4; ++r)
          red[w][mi * 8 + ni * 4 + r][l] = acc[mi][ni][r];
    __syncthreads();

#pragma unroll
    for (int s = 0; s < 2; ++s) {
      int slot = t + s * NTHR;                 // 1024 slots = 16 regs x 64 lanes
      int reg = slot >> 6, lane = slot & 63;
      float v = 0.f;
#pragma unroll
      for (int ww = 0; ww < 8; ++ww) v += red[ww][reg][lane];
      int mi = reg >> 3, ni = (reg >> 2) & 1, r = reg & 3;
      int row = i0 + mi * 16 + (lane >> 4) * 4 + r;  // C/D: col=lane&15, row=(lane>>4)*4+reg
      int col = n0 + ni * 16 + (lane & 15);
      m[(size_t)row * NCOL + col] = v;
    }
  }
  barrier_arrive(&ctr[1]);

  // ---- P2: copy x slice -> out (overlaps other blocks' GEMM tail + barrier skew) ----
  {
    const float4* x4 = reinterpret_cast<const float4*>(x);
    int idx = bid * 2048 + t;
#pragma unroll
    for (int it = 0; it < 4; ++it, idx += NTHR) {
      int i = idx >> 9, c4 = idx & 511;
      *reinterpret_cast<float4*>(&out[(size_t)i * OUTF + c4 * 4]) = x4[idx];
    }
  }
  barrier_wait(&ctr[1]);

  // ---- P3: pairwise L1+exp.  Block = 4 i-rows; jc = t>>5 (16 chunks x 64 j). ----
  {
    typedef float red2_t[16][4][33];
    red2_t& red2 = *reinterpret_cast<red2_t*>(smem);
    int k  = t & 31;
    int jc = t >> 5;
    int i0 = bid * 4;
    int j0 = jc * 64;

    const float4* mv = reinterpret_cast<const float4*>(m);
    float4 a0[4], a1[4];
#pragma unroll
    for (int r = 0; r < 4; ++r) {
      a0[r] = mv[(size_t)(i0 + r) * 64 + k * 2];
      a1[r] = mv[(size_t)(i0 + r) * 64 + k * 2 + 1];
    }

    float acc[4] = {0.f, 0.f, 0.f, 0.f};
#pragma unroll 2
    for (int jj = 0; jj < 64; ++jj) {
      int j = j0 + jj;
      float4 c0 = mv[(size_t)j * 64 + k * 2];
      float4 c1 = mv[(size_t)j * 64 + k * 2 + 1];
#pragma unroll
      for (int r = 0; r < 4; ++r) {
        float s = fabsf(a0[r].x - c0.x) + fabsf(a0[r].y - c0.y) +
                  fabsf(a0[r].z - c0.z) + fabsf(a0[r].w - c0.w) +
                  fabsf(a1[r].x - c1.x) + fabsf(a1[r].y - c1.y) +
                  fabsf(a1[r].z - c1.z) + fabsf(a1[r].w - c1.w);
        acc[r] += __expf(-s);
      }
    }

    __syncthreads();   // smem reuse (after barrier_wait's sync this is safe ordering)
#pragma unroll
    for (int r = 0; r < 4; ++r) red2[jc][r][k] = acc[r];
    __syncthreads();

    if (t < 128) {
      int r = t >> 5, kk = t & 31;
      float s = 0.f;
#pragma unroll
      for (int c = 0; c < 16; ++c) s += red2[c][r][kk];
      out[(size_t)(i0 + r) * OUTF + F_SZ + kk] = s;
    }
  }
}

extern "C" void kernel_launch(void* const* d_in, const int* in_sizes, int n_in,
                              void* d_out, int out_size, void* d_ws, size_t ws_size,
                              hipStream_t stream) {
  const float* x = (const float*)d_in[0];
  const float* W = (const float*)d_in[1];
  float* out = (float*)d_out;
  char* ws = (char*)d_ws;

  const size_t MB = 1u << 20;
  unsigned short* wt = (unsigned short*)ws;        // 1 MB
  float* m = (float*)(ws + MB);                    // 1 MB
  unsigned* ctr = (unsigned*)(ws + 2 * MB);        // 16 B

  hipMemsetAsync(ctr, 0, 16, stream);              // capturable; replay-safe barrier init
  mega<<<dim3(NBLK), NTHR, 0, stream>>>(x, W, out, wt, m, ctr);
}

// Round 8
// 48.568 us; speedup vs baseline: 3.2209x; 3.2209x over previous
//
#include <hip/hip_runtime.h>
#include <hip/hip_bf16.h>

#define B_SZ 1024
#define F_SZ 2048
#define NK   32
#define NCOL 256            // NK*KD
#define OUTF 2080           // F + NK

typedef __attribute__((ext_vector_type(8))) short short8v;
typedef __attribute__((ext_vector_type(8))) unsigned short ushort8v;
typedef __attribute__((ext_vector_type(4))) float f32x4;

static __device__ __forceinline__ unsigned short f2bf(float v) {
  __hip_bfloat16 h = __float2bfloat16(v);   // RNE
  return reinterpret_cast<unsigned short&>(h);
}

// ---------------------------------------------------------------------------
// K1: role-split, 256 blocks x 512 thr.  NO cross-block sync (R3/R7 lesson).
//   blocks 0..127   : LDS-staged bf16 MFMA GEMM -> m[1024][256] f32.
//                     BM=64 BN=32 BK=64, 32 K-steps, 8 waves (4x2) x one
//                     16x16 frag each.  Inline f32->bf16 cvt; B staged via
//                     transposed scatter (R2-proven pattern).
//   blocks 128..255 : copy x rows into out[:, 0:2048] (co-resident with GEMM
//                     blocks; fills their barrier-drain bubbles via m114
//                     MFMA/VMEM co-scheduling).
// ---------------------------------------------------------------------------
__global__ __launch_bounds__(512) void k1_gemm_copy(
    const float* __restrict__ x, const float* __restrict__ W,
    float* __restrict__ m, float* __restrict__ out) {
  int bid = blockIdx.x;
  int t = threadIdx.x;

  if (bid >= 128) {
    // ---------------- copy role ----------------
    const float4* x4 = reinterpret_cast<const float4*>(x);
    int idx = (bid - 128) * 512 + t;
#pragma unroll
    for (int it = 0; it < 8; ++it, idx += 128 * 512) {
      int i  = idx >> 9;          // 512 float4 per x row
      int c4 = idx & 511;
      *reinterpret_cast<float4*>(&out[(size_t)i * OUTF + c4 * 4]) = x4[idx];
    }
    return;
  }

  // ---------------- GEMM role ----------------
  __shared__ __align__(16) unsigned short As[64][72];  // [row][k], +8 pad (144B rows)
  __shared__ __align__(16) unsigned short Bs[32][72];  // [col(n)][k]

  int mt = bid & 15, nt = bid >> 4;     // 16 m-tiles x 8 n-tiles
  int i0 = mt * 64, n0 = nt * 32;

  int w = t >> 6, l = t & 63;
  int wr = w & 3, wc = w >> 2;          // wave grid 4(m) x 2(n), one frag each
  int hi = l >> 4, r16 = l & 15;

  int arow = t >> 3, akq = (t & 7) * 8;     // A staging: 8 f32 -> ushort8
  int bkrow = t >> 3, bn4 = (t & 7) * 4;    // B staging: float4 along n, scatter

  f32x4 acc = (f32x4)(0.f);

  for (int kk = 0; kk < F_SZ; kk += 64) {
    const float* ap = &x[(size_t)(i0 + arow) * F_SZ + kk + akq];
    float4 av0 = *reinterpret_cast<const float4*>(ap);
    float4 av1 = *reinterpret_cast<const float4*>(ap + 4);
    float4 wv = *reinterpret_cast<const float4*>(
        &W[(size_t)(kk + bkrow) * NCOL + n0 + bn4]);

    __syncthreads();   // previous iter's frag reads done before overwrite
    ushort8v a8;
    a8[0] = f2bf(av0.x); a8[1] = f2bf(av0.y); a8[2] = f2bf(av0.z); a8[3] = f2bf(av0.w);
    a8[4] = f2bf(av1.x); a8[5] = f2bf(av1.y); a8[6] = f2bf(av1.z); a8[7] = f2bf(av1.w);
    *reinterpret_cast<ushort8v*>(&As[arow][akq]) = a8;
    Bs[bn4 + 0][bkrow] = f2bf(wv.x);          // transposed scatter (inline W^T)
    Bs[bn4 + 1][bkrow] = f2bf(wv.y);
    Bs[bn4 + 2][bkrow] = f2bf(wv.z);
    Bs[bn4 + 3][bkrow] = f2bf(wv.w);
    __syncthreads();

#pragma unroll
    for (int ks = 0; ks < 2; ++ks) {          // BK=64 = 2 x MFMA-K32
      short8v af = *reinterpret_cast<const short8v*>(&As[wr * 16 + r16][ks * 32 + hi * 8]);
      short8v bf = *reinterpret_cast<const short8v*>(&Bs[wc * 16 + r16][ks * 32 + hi * 8]);
      acc = __builtin_amdgcn_mfma_f32_16x16x32_bf16(af, bf, acc, 0, 0, 0);
    }
  }

#pragma unroll
  for (int r = 0; r < 4; ++r) {
    int row = i0 + wr * 16 + hi * 4 + r;   // C/D: col=lane&15, row=(lane>>4)*4+reg
    int col = n0 + wc * 16 + r16;
    m[(size_t)row * NCOL + col] = acc[r];
  }
}

// ---------------------------------------------------------------------------
// K2: pairwise L1+exp, 256 blocks x 1024 thr (proven R6 structure).
// Block = 4 i-rows; thread (jc=t>>5 over 32 chunks x 32 j, k=t&31) keeps 4
// i-row fragments in registers; LDS reduce; writes out[i][2048+k] directly.
// m (1MB) is L2-resident; VALU-bound.
// ---------------------------------------------------------------------------
__global__ __launch_bounds__(1024) void k2_pairwise(
    const float* __restrict__ m, float* __restrict__ out) {
  __shared__ float red[32][4][33];

  int bid = blockIdx.x;
  int t = threadIdx.x;
  int k  = t & 31;
  int jc = t >> 5;          // 0..31
  int i0 = bid * 4;
  int j0 = jc * 32;

  const float4* mv = reinterpret_cast<const float4*>(m);  // m[i][c]: idx = i*64 + c4
  float4 a0[4], a1[4];
#pragma unroll
  for (int r = 0; r < 4; ++r) {
    a0[r] = mv[(size_t)(i0 + r) * 64 + k * 2];
    a1[r] = mv[(size_t)(i0 + r) * 64 + k * 2 + 1];
  }

  float acc[4] = {0.f, 0.f, 0.f, 0.f};
#pragma unroll 2
  for (int jj = 0; jj < 32; ++jj) {
    int j = j0 + jj;
    float4 c0 = mv[(size_t)j * 64 + k * 2];
    float4 c1 = mv[(size_t)j * 64 + k * 2 + 1];
#pragma unroll
    for (int r = 0; r < 4; ++r) {
      float s = fabsf(a0[r].x - c0.x) + fabsf(a0[r].y - c0.y) +
                fabsf(a0[r].z - c0.z) + fabsf(a0[r].w - c0.w) +
                fabsf(a1[r].x - c1.x) + fabsf(a1[r].y - c1.y) +
                fabsf(a1[r].z - c1.z) + fabsf(a1[r].w - c1.w);
      acc[r] += __expf(-s);
    }
  }

#pragma unroll
  for (int r = 0; r < 4; ++r) red[jc][r][k] = acc[r];
  __syncthreads();

  if (t < 128) {
    int r = t >> 5, kk = t & 31;
    float s = 0.f;
#pragma unroll
    for (int c = 0; c < 32; ++c) s += red[c][r][kk];
    out[(size_t)(i0 + r) * OUTF + F_SZ + kk] = s;
  }
}

extern "C" void kernel_launch(void* const* d_in, const int* in_sizes, int n_in,
                              void* d_out, int out_size, void* d_ws, size_t ws_size,
                              hipStream_t stream) {
  const float* x = (const float*)d_in[0];
  const float* W = (const float*)d_in[1];
  float* out = (float*)d_out;
  float* m = (float*)d_ws;    // 1 MB

  k1_gemm_copy<<<dim3(256), 512, 0, stream>>>(x, W, m, out);
  k2_pairwise<<<dim3(256), 1024, 0, stream>>>(m, out);
}